// Round 1
// baseline (2121.242 us; speedup 1.0000x reference)
//
#include <hip/hip_runtime.h>
#include <hip/hip_bf16.h>

#define GLOBAL_AS __attribute__((address_space(1)))
#define LDS_AS    __attribute__((address_space(3)))

typedef __attribute__((ext_vector_type(4))) float  f32x4;
typedef __attribute__((ext_vector_type(8))) short  bf16x8;

static constexpr int   H      = 128;
static constexpr float BN_EPS = 1e-5f;

__device__ __forceinline__ float bf2f(ushort u) {
  union { unsigned u; float f; } x; x.u = ((unsigned)u) << 16; return x.f;
}
__device__ __forceinline__ ushort f2bf(float f) {
  union { float f; unsigned u; } x; x.f = f;
  unsigned r = x.u + 0x7fffu + ((x.u >> 16) & 1u);
  return (ushort)(r >> 16);
}

// ---------------- weight folding (BN folded into W, b) ----------------
// W [K, NOUT] fp32 row-major -> Wt [NOUT, K] bf16 (i.e. W^T), bout fp32.
__global__ void fold_bf16_kernel(const float* __restrict__ W, const float* __restrict__ b,
                                 const float* __restrict__ bn, int K, int NOUT,
                                 ushort* __restrict__ Wt, float* __restrict__ bout) {
  int idx = blockIdx.x * blockDim.x + threadIdx.x;
  if (idx >= K * NOUT) return;
  int o = idx / K, k = idx - o * K;
  float scale = 1.0f, shift = 0.0f;
  if (bn != nullptr) {
    float g = bn[o], be = bn[NOUT + o], m = bn[2 * NOUT + o], v = bn[3 * NOUT + o];
    scale = g * rsqrtf(v + BN_EPS);
    shift = be - m * scale;
  }
  Wt[(size_t)o * K + k] = f2bf(W[(size_t)k * NOUT + o] * scale);
  if (k == 0) bout[o] = b[o] * scale + shift;
}

__global__ void fold_f32_kernel(const float* __restrict__ W, const float* __restrict__ b,
                                const float* __restrict__ bn, int K, int NOUT,
                                float* __restrict__ Wt, float* __restrict__ bout) {
  int idx = blockIdx.x * blockDim.x + threadIdx.x;
  if (idx >= K * NOUT) return;
  int o = idx / K, k = idx - o * K;
  float scale = 1.0f, shift = 0.0f;
  if (bn != nullptr) {
    float g = bn[o], be = bn[NOUT + o], m = bn[2 * NOUT + o], v = bn[3 * NOUT + o];
    scale = g * rsqrtf(v + BN_EPS);
    shift = be - m * scale;
  }
  Wt[(size_t)o * K + k] = W[(size_t)k * NOUT + o] * scale;
  if (k == 0) bout[o] = b[o] * scale + shift;
}

// ---------------- fp32 -> bf16 convert (x) ----------------
__global__ void cvt4_kernel(const float* __restrict__ x, ushort* __restrict__ xb, int n4) {
  int i = blockIdx.x * blockDim.x + threadIdx.x;
  if (i >= n4) return;
  float4 v = ((const float4*)x)[i];
  ushort4 o; o.x = f2bf(v.x); o.y = f2bf(v.y); o.z = f2bf(v.z); o.w = f2bf(v.w);
  ((ushort4*)xb)[i] = o;
}

// ---------------- CSR build ----------------
__global__ void hist_kernel(const int* __restrict__ idx, int n, int* __restrict__ cnt) {
  int i = blockIdx.x * blockDim.x + threadIdx.x;
  if (i < n) atomicAdd(&cnt[idx[i]], 1);
}

__global__ void block_sum_kernel(const int* __restrict__ v, int n, int* __restrict__ bsum) {
  __shared__ int s[256];
  int i = blockIdx.x * 256 + threadIdx.x;
  int x = (i < n) ? v[i] : 0;
  s[threadIdx.x] = x; __syncthreads();
  for (int off = 128; off > 0; off >>= 1) {
    if (threadIdx.x < (unsigned)off) s[threadIdx.x] += s[threadIdx.x + off];
    __syncthreads();
  }
  if (threadIdx.x == 0) bsum[blockIdx.x] = s[0];
}

__global__ void scan_partials_kernel(int* __restrict__ bsum, int nb,
                                     int* __restrict__ last_out, int total) {
  int acc = 0;
  for (int i = 0; i < nb; ++i) { int t = bsum[i]; bsum[i] = acc; acc += t; }
  if (last_out) *last_out = total;
}

__global__ void scan_final_kernel(const int* __restrict__ v, int n, const int* __restrict__ bsum,
                                  int* __restrict__ rowptr, int* __restrict__ cursor) {
  __shared__ int s[256];
  int i = blockIdx.x * 256 + threadIdx.x;
  int x = (i < n) ? v[i] : 0;
  s[threadIdx.x] = x; __syncthreads();
  for (int off = 1; off < 256; off <<= 1) {
    int add = (threadIdx.x >= (unsigned)off) ? s[threadIdx.x - off] : 0;
    __syncthreads();
    s[threadIdx.x] += add;
    __syncthreads();
  }
  if (i < n) {
    int excl = bsum[blockIdx.x] + s[threadIdx.x] - x;
    rowptr[i] = excl;
    if (cursor) cursor[i] = excl;
  }
}

__global__ void scatter_kernel(const int* __restrict__ src, const int* __restrict__ dst, int n,
                               int* __restrict__ cursor, int* __restrict__ col) {
  int i = blockIdx.x * blockDim.x + threadIdx.x;
  if (i < n) { int p = atomicAdd(&cursor[dst[i]], 1); col[p] = src[i]; }
}

// ---------------- GIN aggregation: z = (1+eps)*h + sum_{src in N(dst)} h[src] ----------------
__global__ __launch_bounds__(256) void agg_kernel(
    const ushort* __restrict__ hb, const float* __restrict__ hf,
    const int* __restrict__ rowptr, const int* __restrict__ col,
    const float* __restrict__ eps_g, int layer,
    ushort* __restrict__ z, int n) {
  int node = blockIdx.x * 4 + (threadIdx.x >> 6);
  if (node >= n) return;
  int lane = threadIdx.x & 63;
  int s = rowptr[node], e = rowptr[node + 1];
  float ax = 0.f, ay = 0.f;
  for (int j = s; j < e; ++j) {
    int sr = col[j];
    ushort2 hv = *(const ushort2*)(hb + (size_t)sr * H + lane * 2);
    ax += bf2f(hv.x); ay += bf2f(hv.y);
  }
  float ep = 1.0f + eps_g[layer];
  float2 hs = *(const float2*)(hf + (size_t)node * H + lane * 2);
  ushort2 o; o.x = f2bf(ep * hs.x + ax); o.y = f2bf(ep * hs.y + ay);
  *(ushort2*)(z + (size_t)node * H + lane * 2) = o;
}

// ---------------- fused GEMM: out = relu(A @ Wt^T + bias) [+ residual] ----------------
// A [M,K] bf16 row-major, Wt [NOUT,K] bf16 (W^T, BN-folded), bias fp32.
// HMODE 0: write bf16 out only. 1: also write fp32 h (no residual). 2: v += h_old, write both.
template<int K, int NOUT, int HMODE>
__global__ __launch_bounds__(256) void gemm_kernel(
    const ushort* __restrict__ A, const ushort* __restrict__ Wt,
    const float* __restrict__ bias,
    ushort* __restrict__ outb, float* __restrict__ hf) {
  constexpr int ROWB = 2 * K;
  __shared__ __align__(16) char lds[64 * ROWB];
  const int t = threadIdx.x;
  const long row0 = (long)blockIdx.x * 64;
  const char* Ab = (const char*)(A + (size_t)row0 * K);

  // stage 64 x K bf16 tile: linear LDS dest, XOR-swizzled global source (rule #21)
  constexpr int ITERS = (64 * ROWB) / (256 * 16);
#pragma unroll
  for (int it = 0; it < ITERS; ++it) {
    int ob = (it * 256 + t) * 16;
    int r = ob / ROWB;
    int c = ob - r * ROWB;
    int sb = r * ROWB + (c ^ ((r & 7) << 4));
    __builtin_amdgcn_global_load_lds((const GLOBAL_AS void*)(Ab + sb),
                                     (LDS_AS void*)(lds + ob), 16, 0, 0);
  }
  __syncthreads();

  const int l  = t & 63;
  const int w  = t >> 6;
  const int lr = l & 15;
  const int lk = l >> 4;
  constexpr int CPW = NOUT / 4;   // columns per wave
  constexpr int NCT = CPW / 16;   // 16-col tiles per wave

  for (int ct = 0; ct < NCT; ++ct) {
    const int colbase = w * CPW + ct * 16;
    f32x4 acc[4] = {};
    const ushort* wp = Wt + (size_t)(colbase + lr) * K + lk * 8;
#pragma unroll
    for (int ks = 0; ks < K / 32; ++ks) {
      bf16x8 bfr = *(const bf16x8*)(wp + ks * 32);
#pragma unroll
      for (int rt = 0; rt < 4; ++rt) {
        const int rr = rt * 16 + lr;
        const int kb = ks * 64 + lk * 16;
        bf16x8 afr = *(const bf16x8*)(lds + rr * ROWB + (kb ^ ((rr & 7) << 4)));
        // swapped operands: lane owns out[row=rt*16+lr][col=colbase+4*lk+j]
        acc[rt] = __builtin_amdgcn_mfma_f32_16x16x32_bf16(bfr, afr, acc[rt], 0, 0, 0);
      }
    }
    const int c0 = colbase + lk * 4;
    const float* bp = bias + c0;
    const float b0 = bp[0], b1 = bp[1], b2 = bp[2], b3 = bp[3];
#pragma unroll
    for (int rt = 0; rt < 4; ++rt) {
      const long grow = row0 + rt * 16 + lr;
      float v0 = fmaxf(acc[rt][0] + b0, 0.f);
      float v1 = fmaxf(acc[rt][1] + b1, 0.f);
      float v2 = fmaxf(acc[rt][2] + b2, 0.f);
      float v3 = fmaxf(acc[rt][3] + b3, 0.f);
      if (HMODE >= 1) {
        float* hp = hf + grow * H + c0;
        if (HMODE == 2) { v0 += hp[0]; v1 += hp[1]; v2 += hp[2]; v3 += hp[3]; }
        hp[0] = v0; hp[1] = v1; hp[2] = v2; hp[3] = v3;
      }
      ushort4 sv; sv.x = f2bf(v0); sv.y = f2bf(v1); sv.z = f2bf(v2); sv.w = f2bf(v3);
      *(ushort4*)(outb + grow * NOUT + c0) = sv;
    }
  }
}

// ---------------- readout: sum / mean / max per graph ----------------
__global__ __launch_bounds__(128) void readout_kernel(const float* __restrict__ hf,
                                                      const int* __restrict__ gptr,
                                                      float* __restrict__ g) {
  int gi = blockIdx.x, t = threadIdx.x;
  int s = gptr[gi], e = gptr[gi + 1];
  float sum = 0.f, mx = -INFINITY;
  for (int n = s; n < e; ++n) {
    float v = hf[(size_t)n * H + t];
    sum += v; mx = fmaxf(mx, v);
  }
  int cnt = e - s;
  g[gi * 384 + t]       = sum;
  g[gi * 384 + 128 + t] = sum / fmaxf((float)cnt, 1.f);
  g[gi * 384 + 256 + t] = (cnt > 0) ? mx : 0.f;
}

// ---------------- classifier head ----------------
__global__ __launch_bounds__(128) void classifier_kernel(
    const float* __restrict__ g,
    const float* __restrict__ W1, const float* __restrict__ b1,
    const float* __restrict__ W2, const float* __restrict__ b2,
    const float* __restrict__ W3, const float* __restrict__ b3,
    float* __restrict__ out) {
  __shared__ float row[384];
  __shared__ float f1[128];
  __shared__ float f2s[64];
  int gi = blockIdx.x, t = threadIdx.x;
  for (int i = t; i < 384; i += 128) row[i] = g[gi * 384 + i];
  __syncthreads();
  float a = b1[t];
  for (int k = 0; k < 384; ++k) a += row[k] * W1[t * 384 + k];
  f1[t] = fmaxf(a, 0.f);
  __syncthreads();
  if (t < 64) {
    float a2 = b2[t];
    for (int k = 0; k < 128; ++k) a2 += f1[k] * W2[t * 128 + k];
    f2s[t] = fmaxf(a2, 0.f);
  }
  __syncthreads();
  if (t < 6) {
    float a3 = b3[t];
    for (int k = 0; k < 64; ++k) a3 += f2s[k] * W3[t * 64 + k];
    out[gi * 6 + t] = a3;
  }
}

// ---------------- launcher ----------------
extern "C" void kernel_launch(void* const* d_in, const int* in_sizes, int n_in,
                              void* d_out, int out_size, void* d_ws, size_t ws_size,
                              hipStream_t stream) {
  (void)n_in; (void)ws_size;
  const float* x     = (const float*)d_in[0];
  const int*   eidx  = (const int*)d_in[1];
  const int*   batch = (const int*)d_in[2];
  const float* in_W  = (const float*)d_in[3];
  const float* in_b  = (const float*)d_in[4];
  const float* in_bn = (const float*)d_in[5];
  const float* W1    = (const float*)d_in[6];
  const float* b1    = (const float*)d_in[7];
  const float* bn1   = (const float*)d_in[8];
  const float* W2    = (const float*)d_in[9];
  const float* b2    = (const float*)d_in[10];
  const float* bn2   = (const float*)d_in[11];
  const float* W3    = (const float*)d_in[12];
  const float* b3    = (const float*)d_in[13];
  const float* eps_g = (const float*)d_in[14];
  const float* nbn   = (const float*)d_in[15];
  const float* cW1   = (const float*)d_in[16];
  const float* cb1   = (const float*)d_in[17];
  const float* cbn1  = (const float*)d_in[18];
  const float* cW2   = (const float*)d_in[19];
  const float* cb2   = (const float*)d_in[20];
  const float* cbn2  = (const float*)d_in[21];
  const float* fW    = (const float*)d_in[22];
  const float* fb    = (const float*)d_in[23];

  const int N  = in_sizes[0] / 128;
  const int E  = in_sizes[1] / 2;
  const int G  = out_size / 6;
  const int Mp = ((N + 63) / 64) * 64;
  const int gblocks = Mp / 64;

  char* p = (char*)d_ws;
  auto alloc = [&](size_t bytes) -> char* {
    char* r = p; p += (bytes + 255) & ~(size_t)255; return r;
  };
  ushort* hb     = (ushort*)alloc((size_t)Mp * H * 2);
  ushort* zb     = (ushort*)alloc((size_t)Mp * H * 2);
  ushort* t1     = (ushort*)alloc((size_t)Mp * 384 * 2);   // also holds x_bf16 initially
  ushort* t2     = (ushort*)alloc((size_t)Mp * 256 * 2);
  float*  hf     = (float*)alloc((size_t)Mp * H * 4);
  int*    deg    = (int*)alloc((size_t)N * 4);
  int*    rowptr = (int*)alloc((size_t)(N + 1) * 4);
  int*    cursor = (int*)alloc((size_t)N * 4);
  int*    colx   = (int*)alloc((size_t)E * 4);
  int*    bsum   = (int*)alloc(4096);
  int*    gbsum  = (int*)alloc(1024);
  int*    gcnt   = (int*)alloc((size_t)G * 4);
  int*    gptr   = (int*)alloc((size_t)(G + 1) * 4);
  float*  gbuf   = (float*)alloc((size_t)G * 384 * 4);
  ushort* wIn    = (ushort*)alloc(128 * 128 * 2);
  float*  bIn    = (float*)alloc(128 * 4);
  ushort* w1f    = (ushort*)alloc((size_t)5 * 384 * 128 * 2);
  float*  b1f    = (float*)alloc((size_t)5 * 384 * 4);
  ushort* w2f    = (ushort*)alloc((size_t)5 * 256 * 384 * 2);
  float*  b2f    = (float*)alloc((size_t)5 * 256 * 4);
  ushort* w3f    = (ushort*)alloc((size_t)5 * 128 * 256 * 2);
  float*  b3f    = (float*)alloc((size_t)5 * 128 * 4);
  float*  cw1f   = (float*)alloc(128 * 384 * 4);
  float*  cb1f   = (float*)alloc(128 * 4);
  float*  cw2f   = (float*)alloc(64 * 128 * 4);
  float*  cb2f   = (float*)alloc(64 * 4);
  float*  cw3f   = (float*)alloc(6 * 64 * 4);
  float*  cb3f   = (float*)alloc(6 * 4);

  // ---- weight folding ----
  fold_bf16_kernel<<<(128 * 128 + 255) / 256, 256, 0, stream>>>(in_W, in_b, in_bn, 128, 128, wIn, bIn);
  for (int i = 0; i < 5; ++i) {
    fold_bf16_kernel<<<(128 * 384 + 255) / 256, 256, 0, stream>>>(
        W1 + (size_t)i * 128 * 384, b1 + (size_t)i * 384, bn1 + (size_t)i * 4 * 384,
        128, 384, w1f + (size_t)i * 384 * 128, b1f + (size_t)i * 384);
    fold_bf16_kernel<<<(384 * 256 + 255) / 256, 256, 0, stream>>>(
        W2 + (size_t)i * 384 * 256, b2 + (size_t)i * 256, bn2 + (size_t)i * 4 * 256,
        384, 256, w2f + (size_t)i * 256 * 384, b2f + (size_t)i * 256);
    fold_bf16_kernel<<<(256 * 128 + 255) / 256, 256, 0, stream>>>(
        W3 + (size_t)i * 256 * 128, b3 + (size_t)i * 128, nbn + (size_t)i * 4 * 128,
        256, 128, w3f + (size_t)i * 128 * 256, b3f + (size_t)i * 128);
  }
  fold_f32_kernel<<<(384 * 128 + 255) / 256, 256, 0, stream>>>(cW1, cb1, cbn1, 384, 128, cw1f, cb1f);
  fold_f32_kernel<<<(128 * 64 + 255) / 256, 256, 0, stream>>>(cW2, cb2, cbn2, 128, 64, cw2f, cb2f);
  fold_f32_kernel<<<(64 * 6 + 255) / 256, 256, 0, stream>>>(fW, fb, nullptr, 64, 6, cw3f, cb3f);

  // ---- x -> bf16 (into t1) ----
  cvt4_kernel<<<(N * 128 / 4 + 255) / 256, 256, 0, stream>>>(x, t1, N * 128 / 4);

  // ---- CSR build (by dst) + graph ranges ----
  hipMemsetAsync(deg, 0, (size_t)N * 4, stream);
  hipMemsetAsync(gcnt, 0, (size_t)G * 4, stream);
  hist_kernel<<<(E + 255) / 256, 256, 0, stream>>>(eidx + E, E, deg);
  hist_kernel<<<(N + 255) / 256, 256, 0, stream>>>(batch, N, gcnt);
  const int nb = (N + 255) / 256;
  block_sum_kernel<<<nb, 256, 0, stream>>>(deg, N, bsum);
  scan_partials_kernel<<<1, 1, 0, stream>>>(bsum, nb, rowptr + N, E);
  scan_final_kernel<<<nb, 256, 0, stream>>>(deg, N, bsum, rowptr, cursor);
  const int nbg = (G + 255) / 256;
  block_sum_kernel<<<nbg, 256, 0, stream>>>(gcnt, G, gbsum);
  scan_partials_kernel<<<1, 1, 0, stream>>>(gbsum, nbg, gptr + G, N);
  scan_final_kernel<<<nbg, 256, 0, stream>>>(gcnt, G, gbsum, gptr, nullptr);
  scatter_kernel<<<(E + 255) / 256, 256, 0, stream>>>(eidx, eidx + E, E, cursor, colx);

  // ---- input projection: h = relu(bn(x @ in_W + in_b)) ----
  gemm_kernel<128, 128, 1><<<gblocks, 256, 0, stream>>>(t1, wIn, bIn, hb, hf);

  // ---- GIN layers ----
  for (int i = 0; i < 5; ++i) {
    agg_kernel<<<(N + 3) / 4, 256, 0, stream>>>(hb, hf, rowptr, colx, eps_g, i, zb, N);
    gemm_kernel<128, 384, 0><<<gblocks, 256, 0, stream>>>(
        zb, w1f + (size_t)i * 384 * 128, b1f + (size_t)i * 384, t1, nullptr);
    gemm_kernel<384, 256, 0><<<gblocks, 256, 0, stream>>>(
        t1, w2f + (size_t)i * 256 * 384, b2f + (size_t)i * 256, t2, nullptr);
    if (i == 0)
      gemm_kernel<256, 128, 1><<<gblocks, 256, 0, stream>>>(
          t2, w3f + (size_t)i * 128 * 256, b3f + (size_t)i * 128, hb, hf);
    else
      gemm_kernel<256, 128, 2><<<gblocks, 256, 0, stream>>>(
          t2, w3f + (size_t)i * 128 * 256, b3f + (size_t)i * 128, hb, hf);
  }

  // ---- readout + classifier ----
  readout_kernel<<<G, 128, 0, stream>>>(hf, gptr, gbuf);
  classifier_kernel<<<G, 128, 0, stream>>>(gbuf, cw1f, cb1f, cw2f, cb2f, cw3f, cb3f,
                                           (float*)d_out);
}

// Round 2
// 1662.637 us; speedup vs baseline: 1.2758x; 1.2758x over previous
//
#include <hip/hip_runtime.h>
#include <hip/hip_bf16.h>

#define GLOBAL_AS __attribute__((address_space(1)))
#define LDS_AS    __attribute__((address_space(3)))

typedef __attribute__((ext_vector_type(4))) float  f32x4;
typedef __attribute__((ext_vector_type(8))) short  bf16x8;

static constexpr int   H      = 128;
static constexpr float BN_EPS = 1e-5f;

__device__ __forceinline__ float bf2f(ushort u) {
  union { unsigned u; float f; } x; x.u = ((unsigned)u) << 16; return x.f;
}
__device__ __forceinline__ ushort f2bf(float f) {
  union { float f; unsigned u; } x; x.f = f;
  unsigned r = x.u + 0x7fffu + ((x.u >> 16) & 1u);
  return (ushort)(r >> 16);
}

// ---------------- weight folding (BN folded into W, b) ----------------
// W [K, NOUT] fp32 row-major -> Wt [NOUT, K] bf16 (i.e. W^T), bout fp32.
__global__ void fold_bf16_kernel(const float* __restrict__ W, const float* __restrict__ b,
                                 const float* __restrict__ bn, int K, int NOUT,
                                 ushort* __restrict__ Wt, float* __restrict__ bout) {
  int idx = blockIdx.x * blockDim.x + threadIdx.x;
  if (idx >= K * NOUT) return;
  int o = idx / K, k = idx - o * K;
  float scale = 1.0f, shift = 0.0f;
  if (bn != nullptr) {
    float g = bn[o], be = bn[NOUT + o], m = bn[2 * NOUT + o], v = bn[3 * NOUT + o];
    scale = g * rsqrtf(v + BN_EPS);
    shift = be - m * scale;
  }
  Wt[(size_t)o * K + k] = f2bf(W[(size_t)k * NOUT + o] * scale);
  if (k == 0) bout[o] = b[o] * scale + shift;
}

__global__ void fold_f32_kernel(const float* __restrict__ W, const float* __restrict__ b,
                                const float* __restrict__ bn, int K, int NOUT,
                                float* __restrict__ Wt, float* __restrict__ bout) {
  int idx = blockIdx.x * blockDim.x + threadIdx.x;
  if (idx >= K * NOUT) return;
  int o = idx / K, k = idx - o * K;
  float scale = 1.0f, shift = 0.0f;
  if (bn != nullptr) {
    float g = bn[o], be = bn[NOUT + o], m = bn[2 * NOUT + o], v = bn[3 * NOUT + o];
    scale = g * rsqrtf(v + BN_EPS);
    shift = be - m * scale;
  }
  Wt[(size_t)o * K + k] = W[(size_t)k * NOUT + o] * scale;
  if (k == 0) bout[o] = b[o] * scale + shift;
}

// ---------------- fp32 -> bf16 convert (x) ----------------
__global__ void cvt4_kernel(const float* __restrict__ x, ushort* __restrict__ xb, int n4) {
  int i = blockIdx.x * blockDim.x + threadIdx.x;
  if (i >= n4) return;
  float4 v = ((const float4*)x)[i];
  ushort4 o; o.x = f2bf(v.x); o.y = f2bf(v.y); o.z = f2bf(v.z); o.w = f2bf(v.w);
  ((ushort4*)xb)[i] = o;
}

// ---------------- CSR build ----------------
__global__ void hist_kernel(const int* __restrict__ idx, int n, int* __restrict__ cnt) {
  int i = blockIdx.x * blockDim.x + threadIdx.x;
  if (i < n) atomicAdd(&cnt[idx[i]], 1);
}

__global__ void block_sum_kernel(const int* __restrict__ v, int n, int* __restrict__ bsum) {
  __shared__ int s[256];
  int i = blockIdx.x * 256 + threadIdx.x;
  int x = (i < n) ? v[i] : 0;
  s[threadIdx.x] = x; __syncthreads();
  for (int off = 128; off > 0; off >>= 1) {
    if (threadIdx.x < (unsigned)off) s[threadIdx.x] += s[threadIdx.x + off];
    __syncthreads();
  }
  if (threadIdx.x == 0) bsum[blockIdx.x] = s[0];
}

// single-block chunked exclusive scan of bsum[0..nb) (replaces serial 1-thread scan)
__global__ void scan_block_kernel(int* __restrict__ bsum, int nb,
                                  int* __restrict__ last_out, int total) {
  __shared__ int s[256];
  __shared__ int carry;
  if (threadIdx.x == 0) carry = 0;
  __syncthreads();
  for (int base = 0; base < nb; base += 256) {
    int i = base + threadIdx.x;
    int x = (i < nb) ? bsum[i] : 0;
    s[threadIdx.x] = x; __syncthreads();
    for (int off = 1; off < 256; off <<= 1) {
      int add = (threadIdx.x >= (unsigned)off) ? s[threadIdx.x - off] : 0;
      __syncthreads();
      s[threadIdx.x] += add;
      __syncthreads();
    }
    if (i < nb) bsum[i] = carry + s[threadIdx.x] - x;   // exclusive
    __syncthreads();
    if (threadIdx.x == 0) carry += s[255];
    __syncthreads();
  }
  if (last_out && threadIdx.x == 0) *last_out = total;
}

__global__ void scan_final_kernel(const int* __restrict__ v, int n, const int* __restrict__ bsum,
                                  int* __restrict__ rowptr, int* __restrict__ cursor) {
  __shared__ int s[256];
  int i = blockIdx.x * 256 + threadIdx.x;
  int x = (i < n) ? v[i] : 0;
  s[threadIdx.x] = x; __syncthreads();
  for (int off = 1; off < 256; off <<= 1) {
    int add = (threadIdx.x >= (unsigned)off) ? s[threadIdx.x - off] : 0;
    __syncthreads();
    s[threadIdx.x] += add;
    __syncthreads();
  }
  if (i < n) {
    int excl = bsum[blockIdx.x] + s[threadIdx.x] - x;
    rowptr[i] = excl;
    if (cursor) cursor[i] = excl;
  }
}

__global__ void scatter_kernel(const int* __restrict__ src, const int* __restrict__ dst, int n,
                               int* __restrict__ cursor, int* __restrict__ col) {
  int i = blockIdx.x * blockDim.x + threadIdx.x;
  if (i < n) { int p = atomicAdd(&cursor[dst[i]], 1); col[p] = src[i]; }
}

// ---------------- GIN aggregation: z = (1+eps)*h + sum_{src in N(dst)} h[src] ----------------
// One node per wave; edge loop unrolled x8 so 8 row-gathers are in flight per wave
// (round-0 profile: serial gather loop was latency-bound at 1.5 TB/s).
__global__ __launch_bounds__(256) void agg_kernel(
    const ushort* __restrict__ hb, const float* __restrict__ hf,
    const int* __restrict__ rowptr, const int* __restrict__ col,
    const float* __restrict__ eps_g, int layer,
    ushort* __restrict__ z, int n) {
  int node = blockIdx.x * 4 + (threadIdx.x >> 6);
  if (node >= n) return;
  int lane = threadIdx.x & 63;
  int s = rowptr[node], e = rowptr[node + 1];
  float ax = 0.f, ay = 0.f;
  const size_t lo = (size_t)lane * 2;
  int j = s;
  for (; j + 8 <= e; j += 8) {
    int i0 = col[j + 0], i1 = col[j + 1], i2 = col[j + 2], i3 = col[j + 3];
    int i4 = col[j + 4], i5 = col[j + 5], i6 = col[j + 6], i7 = col[j + 7];
    ushort2 h0 = *(const ushort2*)(hb + (size_t)i0 * H + lo);
    ushort2 h1 = *(const ushort2*)(hb + (size_t)i1 * H + lo);
    ushort2 h2 = *(const ushort2*)(hb + (size_t)i2 * H + lo);
    ushort2 h3 = *(const ushort2*)(hb + (size_t)i3 * H + lo);
    ushort2 h4 = *(const ushort2*)(hb + (size_t)i4 * H + lo);
    ushort2 h5 = *(const ushort2*)(hb + (size_t)i5 * H + lo);
    ushort2 h6 = *(const ushort2*)(hb + (size_t)i6 * H + lo);
    ushort2 h7 = *(const ushort2*)(hb + (size_t)i7 * H + lo);
    ax += bf2f(h0.x) + bf2f(h1.x) + bf2f(h2.x) + bf2f(h3.x)
        + bf2f(h4.x) + bf2f(h5.x) + bf2f(h6.x) + bf2f(h7.x);
    ay += bf2f(h0.y) + bf2f(h1.y) + bf2f(h2.y) + bf2f(h3.y)
        + bf2f(h4.y) + bf2f(h5.y) + bf2f(h6.y) + bf2f(h7.y);
  }
  if (j + 4 <= e) {
    int i0 = col[j + 0], i1 = col[j + 1], i2 = col[j + 2], i3 = col[j + 3];
    ushort2 h0 = *(const ushort2*)(hb + (size_t)i0 * H + lo);
    ushort2 h1 = *(const ushort2*)(hb + (size_t)i1 * H + lo);
    ushort2 h2 = *(const ushort2*)(hb + (size_t)i2 * H + lo);
    ushort2 h3 = *(const ushort2*)(hb + (size_t)i3 * H + lo);
    ax += bf2f(h0.x) + bf2f(h1.x) + bf2f(h2.x) + bf2f(h3.x);
    ay += bf2f(h0.y) + bf2f(h1.y) + bf2f(h2.y) + bf2f(h3.y);
    j += 4;
  }
  for (; j < e; ++j) {
    ushort2 hv = *(const ushort2*)(hb + (size_t)col[j] * H + lo);
    ax += bf2f(hv.x); ay += bf2f(hv.y);
  }
  float ep = 1.0f + eps_g[layer];
  float2 hs = *(const float2*)(hf + (size_t)node * H + lane * 2);
  ushort2 o; o.x = f2bf(ep * hs.x + ax); o.y = f2bf(ep * hs.y + ay);
  *(ushort2*)(z + (size_t)node * H + lane * 2) = o;
}

// ---------------- fused GEMM: out = relu(A @ Wt^T + bias) [+ residual] ----------------
// A [M,K] bf16 row-major, Wt [NOUT,K] bf16 (W^T, BN-folded), bias fp32.
// HMODE 0: write bf16 out only. 1: also write fp32 h (no residual). 2: v += h_old, write both.
template<int K, int NOUT, int HMODE>
__global__ __launch_bounds__(256) void gemm_kernel(
    const ushort* __restrict__ A, const ushort* __restrict__ Wt,
    const float* __restrict__ bias,
    ushort* __restrict__ outb, float* __restrict__ hf) {
  constexpr int ROWB = 2 * K;
  __shared__ __align__(16) char lds[64 * ROWB];
  const int t = threadIdx.x;
  const long row0 = (long)blockIdx.x * 64;
  const char* Ab = (const char*)(A + (size_t)row0 * K);

  // stage 64 x K bf16 tile: linear LDS dest, XOR-swizzled global source (rule #21)
  constexpr int ITERS = (64 * ROWB) / (256 * 16);
#pragma unroll
  for (int it = 0; it < ITERS; ++it) {
    int ob = (it * 256 + t) * 16;
    int r = ob / ROWB;
    int c = ob - r * ROWB;
    int sb = r * ROWB + (c ^ ((r & 7) << 4));
    __builtin_amdgcn_global_load_lds((const GLOBAL_AS void*)(Ab + sb),
                                     (LDS_AS void*)(lds + ob), 16, 0, 0);
  }
  __syncthreads();

  const int l  = t & 63;
  const int w  = t >> 6;
  const int lr = l & 15;
  const int lk = l >> 4;
  constexpr int CPW = NOUT / 4;   // columns per wave
  constexpr int NCT = CPW / 16;   // 16-col tiles per wave

  for (int ct = 0; ct < NCT; ++ct) {
    const int colbase = w * CPW + ct * 16;
    f32x4 acc[4] = {};
    const ushort* wp = Wt + (size_t)(colbase + lr) * K + lk * 8;
#pragma unroll
    for (int ks = 0; ks < K / 32; ++ks) {
      bf16x8 bfr = *(const bf16x8*)(wp + ks * 32);
#pragma unroll
      for (int rt = 0; rt < 4; ++rt) {
        const int rr = rt * 16 + lr;
        const int kb = ks * 64 + lk * 16;
        bf16x8 afr = *(const bf16x8*)(lds + rr * ROWB + (kb ^ ((rr & 7) << 4)));
        // swapped operands: lane owns out[row=rt*16+lr][col=colbase+4*lk+j]
        acc[rt] = __builtin_amdgcn_mfma_f32_16x16x32_bf16(bfr, afr, acc[rt], 0, 0, 0);
      }
    }
    const int c0 = colbase + lk * 4;
    const float* bp = bias + c0;
    const float b0 = bp[0], b1 = bp[1], b2 = bp[2], b3 = bp[3];
#pragma unroll
    for (int rt = 0; rt < 4; ++rt) {
      const long grow = row0 + rt * 16 + lr;
      float v0 = fmaxf(acc[rt][0] + b0, 0.f);
      float v1 = fmaxf(acc[rt][1] + b1, 0.f);
      float v2 = fmaxf(acc[rt][2] + b2, 0.f);
      float v3 = fmaxf(acc[rt][3] + b3, 0.f);
      if (HMODE >= 1) {
        float4* hp = (float4*)(hf + grow * H + c0);
        if (HMODE == 2) {
          float4 o = *hp;
          v0 += o.x; v1 += o.y; v2 += o.z; v3 += o.w;
        }
        *hp = make_float4(v0, v1, v2, v3);
      }
      ushort4 sv; sv.x = f2bf(v0); sv.y = f2bf(v1); sv.z = f2bf(v2); sv.w = f2bf(v3);
      *(ushort4*)(outb + grow * NOUT + c0) = sv;
    }
  }
}

// ---------------- readout: sum / mean / max per graph ----------------
__global__ __launch_bounds__(128) void readout_kernel(const float* __restrict__ hf,
                                                      const int* __restrict__ gptr,
                                                      float* __restrict__ g) {
  int gi = blockIdx.x, t = threadIdx.x;
  int s = gptr[gi], e = gptr[gi + 1];
  float sum = 0.f, mx = -INFINITY;
  for (int n = s; n < e; ++n) {
    float v = hf[(size_t)n * H + t];
    sum += v; mx = fmaxf(mx, v);
  }
  int cnt = e - s;
  g[gi * 384 + t]       = sum;
  g[gi * 384 + 128 + t] = sum / fmaxf((float)cnt, 1.f);
  g[gi * 384 + 256 + t] = (cnt > 0) ? mx : 0.f;
}

// ---------------- classifier head ----------------
__global__ __launch_bounds__(128) void classifier_kernel(
    const float* __restrict__ g,
    const float* __restrict__ W1, const float* __restrict__ b1,
    const float* __restrict__ W2, const float* __restrict__ b2,
    const float* __restrict__ W3, const float* __restrict__ b3,
    float* __restrict__ out) {
  __shared__ float row[384];
  __shared__ float f1[128];
  __shared__ float f2s[64];
  int gi = blockIdx.x, t = threadIdx.x;
  for (int i = t; i < 384; i += 128) row[i] = g[gi * 384 + i];
  __syncthreads();
  float a = b1[t];
  for (int k = 0; k < 384; ++k) a += row[k] * W1[t * 384 + k];
  f1[t] = fmaxf(a, 0.f);
  __syncthreads();
  if (t < 64) {
    float a2 = b2[t];
    for (int k = 0; k < 128; ++k) a2 += f1[k] * W2[t * 128 + k];
    f2s[t] = fmaxf(a2, 0.f);
  }
  __syncthreads();
  if (t < 6) {
    float a3 = b3[t];
    for (int k = 0; k < 64; ++k) a3 += f2s[k] * W3[t * 64 + k];
    out[gi * 6 + t] = a3;
  }
}

// ---------------- launcher ----------------
extern "C" void kernel_launch(void* const* d_in, const int* in_sizes, int n_in,
                              void* d_out, int out_size, void* d_ws, size_t ws_size,
                              hipStream_t stream) {
  (void)n_in; (void)ws_size;
  const float* x     = (const float*)d_in[0];
  const int*   eidx  = (const int*)d_in[1];
  const int*   batch = (const int*)d_in[2];
  const float* in_W  = (const float*)d_in[3];
  const float* in_b  = (const float*)d_in[4];
  const float* in_bn = (const float*)d_in[5];
  const float* W1    = (const float*)d_in[6];
  const float* b1    = (const float*)d_in[7];
  const float* bn1   = (const float*)d_in[8];
  const float* W2    = (const float*)d_in[9];
  const float* b2    = (const float*)d_in[10];
  const float* bn2   = (const float*)d_in[11];
  const float* W3    = (const float*)d_in[12];
  const float* b3    = (const float*)d_in[13];
  const float* eps_g = (const float*)d_in[14];
  const float* nbn   = (const float*)d_in[15];
  const float* cW1   = (const float*)d_in[16];
  const float* cb1   = (const float*)d_in[17];
  const float* cbn1  = (const float*)d_in[18];
  const float* cW2   = (const float*)d_in[19];
  const float* cb2   = (const float*)d_in[20];
  const float* cbn2  = (const float*)d_in[21];
  const float* fW    = (const float*)d_in[22];
  const float* fb    = (const float*)d_in[23];

  const int N  = in_sizes[0] / 128;
  const int E  = in_sizes[1] / 2;
  const int G  = out_size / 6;
  const int Mp = ((N + 63) / 64) * 64;
  const int gblocks = Mp / 64;

  char* p = (char*)d_ws;
  auto alloc = [&](size_t bytes) -> char* {
    char* r = p; p += (bytes + 255) & ~(size_t)255; return r;
  };
  ushort* hb     = (ushort*)alloc((size_t)Mp * H * 2);
  ushort* zb     = (ushort*)alloc((size_t)Mp * H * 2);
  ushort* t1     = (ushort*)alloc((size_t)Mp * 384 * 2);   // also holds x_bf16 initially
  ushort* t2     = (ushort*)alloc((size_t)Mp * 256 * 2);
  float*  hf     = (float*)alloc((size_t)Mp * H * 4);
  int*    deg    = (int*)alloc((size_t)N * 4);
  int*    rowptr = (int*)alloc((size_t)(N + 1) * 4);
  int*    cursor = (int*)alloc((size_t)N * 4);
  int*    colx   = (int*)alloc((size_t)E * 4);
  int*    bsum   = (int*)alloc(4096);
  int*    gbsum  = (int*)alloc(1024);
  int*    gcnt   = (int*)alloc((size_t)G * 4);
  int*    gptr   = (int*)alloc((size_t)(G + 1) * 4);
  float*  gbuf   = (float*)alloc((size_t)G * 384 * 4);
  ushort* wIn    = (ushort*)alloc(128 * 128 * 2);
  float*  bIn    = (float*)alloc(128 * 4);
  ushort* w1f    = (ushort*)alloc((size_t)5 * 384 * 128 * 2);
  float*  b1f    = (float*)alloc((size_t)5 * 384 * 4);
  ushort* w2f    = (ushort*)alloc((size_t)5 * 256 * 384 * 2);
  float*  b2f    = (float*)alloc((size_t)5 * 256 * 4);
  ushort* w3f    = (ushort*)alloc((size_t)5 * 128 * 256 * 2);
  float*  b3f    = (float*)alloc((size_t)5 * 128 * 4);
  float*  cw1f   = (float*)alloc(128 * 384 * 4);
  float*  cb1f   = (float*)alloc(128 * 4);
  float*  cw2f   = (float*)alloc(64 * 128 * 4);
  float*  cb2f   = (float*)alloc(64 * 4);
  float*  cw3f   = (float*)alloc(6 * 64 * 4);
  float*  cb3f   = (float*)alloc(6 * 4);

  // ---- weight folding ----
  fold_bf16_kernel<<<(128 * 128 + 255) / 256, 256, 0, stream>>>(in_W, in_b, in_bn, 128, 128, wIn, bIn);
  for (int i = 0; i < 5; ++i) {
    fold_bf16_kernel<<<(128 * 384 + 255) / 256, 256, 0, stream>>>(
        W1 + (size_t)i * 128 * 384, b1 + (size_t)i * 384, bn1 + (size_t)i * 4 * 384,
        128, 384, w1f + (size_t)i * 384 * 128, b1f + (size_t)i * 384);
    fold_bf16_kernel<<<(384 * 256 + 255) / 256, 256, 0, stream>>>(
        W2 + (size_t)i * 384 * 256, b2 + (size_t)i * 256, bn2 + (size_t)i * 4 * 256,
        384, 256, w2f + (size_t)i * 256 * 384, b2f + (size_t)i * 256);
    fold_bf16_kernel<<<(256 * 128 + 255) / 256, 256, 0, stream>>>(
        W3 + (size_t)i * 256 * 128, b3 + (size_t)i * 128, nbn + (size_t)i * 4 * 128,
        256, 128, w3f + (size_t)i * 128 * 256, b3f + (size_t)i * 128);
  }
  fold_f32_kernel<<<(384 * 128 + 255) / 256, 256, 0, stream>>>(cW1, cb1, cbn1, 384, 128, cw1f, cb1f);
  fold_f32_kernel<<<(128 * 64 + 255) / 256, 256, 0, stream>>>(cW2, cb2, cbn2, 128, 64, cw2f, cb2f);
  fold_f32_kernel<<<(64 * 6 + 255) / 256, 256, 0, stream>>>(fW, fb, nullptr, 64, 6, cw3f, cb3f);

  // ---- x -> bf16 (into t1) ----
  cvt4_kernel<<<(N * 128 / 4 + 255) / 256, 256, 0, stream>>>(x, t1, N * 128 / 4);

  // ---- CSR build (by dst) + graph ranges ----
  hipMemsetAsync(deg, 0, (size_t)N * 4, stream);
  hipMemsetAsync(gcnt, 0, (size_t)G * 4, stream);
  hist_kernel<<<(E + 255) / 256, 256, 0, stream>>>(eidx + E, E, deg);
  hist_kernel<<<(N + 255) / 256, 256, 0, stream>>>(batch, N, gcnt);
  const int nb = (N + 255) / 256;
  block_sum_kernel<<<nb, 256, 0, stream>>>(deg, N, bsum);
  scan_block_kernel<<<1, 256, 0, stream>>>(bsum, nb, rowptr + N, E);
  scan_final_kernel<<<nb, 256, 0, stream>>>(deg, N, bsum, rowptr, cursor);
  const int nbg = (G + 255) / 256;
  block_sum_kernel<<<nbg, 256, 0, stream>>>(gcnt, G, gbsum);
  scan_block_kernel<<<1, 256, 0, stream>>>(gbsum, nbg, gptr + G, N);
  scan_final_kernel<<<nbg, 256, 0, stream>>>(gcnt, G, gbsum, gptr, nullptr);
  scatter_kernel<<<(E + 255) / 256, 256, 0, stream>>>(eidx, eidx + E, E, cursor, colx);

  // ---- input projection: h = relu(bn(x @ in_W + in_b)) ----
  gemm_kernel<128, 128, 1><<<gblocks, 256, 0, stream>>>(t1, wIn, bIn, hb, hf);

  // ---- GIN layers ----
  for (int i = 0; i < 5; ++i) {
    agg_kernel<<<(N + 3) / 4, 256, 0, stream>>>(hb, hf, rowptr, colx, eps_g, i, zb, N);
    gemm_kernel<128, 384, 0><<<gblocks, 256, 0, stream>>>(
        zb, w1f + (size_t)i * 384 * 128, b1f + (size_t)i * 384, t1, nullptr);
    gemm_kernel<384, 256, 0><<<gblocks, 256, 0, stream>>>(
        t1, w2f + (size_t)i * 256 * 384, b2f + (size_t)i * 256, t2, nullptr);
    if (i == 0)
      gemm_kernel<256, 128, 1><<<gblocks, 256, 0, stream>>>(
          t2, w3f + (size_t)i * 128 * 256, b3f + (size_t)i * 128, hb, hf);
    else
      gemm_kernel<256, 128, 2><<<gblocks, 256, 0, stream>>>(
          t2, w3f + (size_t)i * 128 * 256, b3f + (size_t)i * 128, hb, hf);
  }

  // ---- readout + classifier ----
  readout_kernel<<<G, 128, 0, stream>>>(hf, gptr, gbuf);
  classifier_kernel<<<G, 128, 0, stream>>>(gbuf, cw1f, cb1f, cw2f, cb2f, cw3f, cb3f,
                                           (float*)d_out);
}